// Round 1
// baseline (324.089 us; speedup 1.0000x reference)
//
#include <hip/hip_runtime.h>

// ---------------------------------------------------------------------------
// Attention_33638183862624  (linear "Taylor-softmax" attention)
// B=16, C=512, CQK=64, N=4096.  fp32 in/out, bf16 MFMA internally (tol = 2%
// of ref absmax).  V is never materialized:
//   T[m,k]   = sum_n Kn[m,n] x[k,n]
//   matrix   = T * Wv^T + bv (x) Ksum
//   Vsum[c]  = Wv[c,:]*xsum + N*bv[c]
//   out[c,n] = gamma * tailor[n] * (Vsum[c] + sum_m Qn[m,n]*matrix[m,c])
// ---------------------------------------------------------------------------

typedef __attribute__((ext_vector_type(8))) short short8_t;
typedef __attribute__((ext_vector_type(4))) float f32x4;

__device__ __forceinline__ unsigned short f2bf(float f) {
  union { float f; unsigned u; } v; v.f = f;
  unsigned r = v.u + 0x7FFFu + ((v.u >> 16) & 1u);   // RNE
  return (unsigned short)(r >> 16);
}
__device__ __forceinline__ float bf2f(unsigned short h) {
  union { unsigned u; float f; } v; v.u = ((unsigned)h) << 16;
  return v.f;
}

#define MFMA(a, b, c) __builtin_amdgcn_mfma_f32_16x16x32_bf16((a), (b), (c), 0, 0, 0)

// ---------------------------------------------------------------------------
// k_prep: pack Wq (rows 0..63) and Wk (rows 64..127) into bf16 [128][512]
// ---------------------------------------------------------------------------
__global__ void k_prep(const float* __restrict__ Wq, const float* __restrict__ Wk,
                       unsigned short* __restrict__ Wqk) {
  int idx = blockIdx.x * 256 + threadIdx.x;       // 65536 total
  int o = idx >> 9, c = idx & 511;
  float v = (o < 64) ? Wq[o * 512 + c] : Wk[(o - 64) * 512 + c];
  Wqk[idx] = f2bf(v);
}

// ---------------------------------------------------------------------------
// k_qk: per batch GEMM  QK[128 o][4096 n] = Wqk[128][512] * x[512][4096]
// tile 128o x 128n, K-chunks of 32.  Fused epilogue: +bias, column L2 norm,
// writes QnT[b][n][64] bf16 (transposed) and Kn[b][64][n] bf16, Ksum atomics.
// grid (32 ntiles, 16 batches), 256 threads.
// ---------------------------------------------------------------------------
__launch_bounds__(256, 2)
__global__ void k_qk(const float* __restrict__ x, const unsigned short* __restrict__ Wqk,
                     const float* __restrict__ bq, const float* __restrict__ bk,
                     unsigned short* __restrict__ QnT, unsigned short* __restrict__ KnG,
                     float* __restrict__ Ksum) {
  __shared__ __align__(16) unsigned char smem[39424];
  unsigned short* SA = (unsigned short*)smem;             // 128 rows x 40 shorts
  unsigned short* SB = (unsigned short*)(smem + 10240);   // 128 rows x 40 shorts
  unsigned short* EQ = (unsigned short*)smem;             // 128 rows x 72 shorts
  unsigned short* EK = (unsigned short*)(smem + 18432);   // 64 rows x 136 shorts
  float* ssq   = (float*)(smem + 35840);                  // [4][128]
  float* invq  = (float*)(smem + 37888);                  // [128]
  float* invk  = (float*)(smem + 38400);                  // [128]
  float* biasL = (float*)(smem + 38912);                  // [128]

  const int t = threadIdx.x;
  const int lane = t & 63, w = t >> 6;
  const int l15 = lane & 15, quad = lane >> 4;
  const int nt = blockIdx.x, b = blockIdx.y;
  const int n0 = nt * 128;
  const float* xb = x + (size_t)b * 512 * 4096;

  if (t < 128) biasL[t] = (t < 64) ? bq[t] : bk[t - 64];

  f32x4 acc[2][8];
#pragma unroll
  for (int i = 0; i < 2; ++i)
#pragma unroll
    for (int j = 0; j < 8; ++j) acc[i][j] = (f32x4){0.f, 0.f, 0.f, 0.f};

  const int nB = t & 127;     // column handled by this thread in B-staging
  const int cgB = t >> 7;     // 0/1

  for (int kc = 0; kc < 16; ++kc) {
    const int c0 = kc * 32;
    __syncthreads();
    // stage A: Wqk[0..128][c0..c0+32] (already bf16) -> SA[o][c]
#pragma unroll
    for (int p = 0; p < 2; ++p) {
      int idx = t + p * 256;
      int o = idx >> 2, seg = idx & 3;
      *(short8_t*)(SA + o * 40 + seg * 8) =
          *(const short8_t*)(Wqk + o * 512 + c0 + seg * 8);
    }
    // stage B (transpose): x[c][n0+n] -> SB[n][c], 16B per thread-write
#pragma unroll
    for (int g = 0; g < 2; ++g) {
      int cb = c0 + cgB * 8 + g * 16;
      const float* src = xb + (size_t)cb * 4096 + n0 + nB;
      short8_t v;
#pragma unroll
      for (int i = 0; i < 8; ++i) v[i] = (short)f2bf(src[(size_t)i * 4096]);
      *(short8_t*)(SB + nB * 40 + cgB * 8 + g * 16) = v;
    }
    __syncthreads();
    short8_t a0 = *(const short8_t*)(SA + (w * 32 + l15) * 40 + quad * 8);
    short8_t a1 = *(const short8_t*)(SA + (w * 32 + 16 + l15) * 40 + quad * 8);
#pragma unroll
    for (int tc = 0; tc < 8; ++tc) {
      short8_t bfr = *(const short8_t*)(SB + (tc * 16 + l15) * 40 + quad * 8);
      acc[0][tc] = MFMA(a0, bfr, acc[0][tc]);
      acc[1][tc] = MFMA(a1, bfr, acc[1][tc]);
    }
  }
  __syncthreads();

  // add bias (per output channel o)
#pragma unroll
  for (int trl = 0; trl < 2; ++trl)
#pragma unroll
    for (int reg = 0; reg < 4; ++reg) {
      int o = w * 32 + trl * 16 + quad * 4 + reg;
      float bias = biasL[o];
#pragma unroll
      for (int tc = 0; tc < 8; ++tc) acc[trl][tc][reg] += bias;
    }

  // per-column sum of squares: reduce this wave's 32-o slice per column
#pragma unroll
  for (int tc = 0; tc < 8; ++tc) {
    float v = 0.f;
#pragma unroll
    for (int trl = 0; trl < 2; ++trl)
#pragma unroll
      for (int reg = 0; reg < 4; ++reg) {
        float q = acc[trl][tc][reg];
        v += q * q;
      }
    v += __shfl_xor(v, 16);
    v += __shfl_xor(v, 32);
    if (quad == 0) ssq[w * 128 + tc * 16 + l15] = v;
  }
  __syncthreads();
  if (t < 128) {
    float qs = ssq[t] + ssq[128 + t];
    float ks = ssq[256 + t] + ssq[384 + t];
    invq[t] = 1.0f / fmaxf(sqrtf(qs), 1e-6f);
    invk[t] = 1.0f / fmaxf(sqrtf(ks), 1e-6f);
  }
  __syncthreads();

  if (w < 2) {
    // Q waves (o 0..63): write normalized, transposed, into EQ[n][o]
#pragma unroll
    for (int trl = 0; trl < 2; ++trl)
#pragma unroll
      for (int tc = 0; tc < 8; ++tc) {
        int n = tc * 16 + l15;
        float inv = invq[n];
#pragma unroll
        for (int reg = 0; reg < 4; ++reg) {
          int o = w * 32 + trl * 16 + quad * 4 + reg;
          EQ[n * 72 + o] = f2bf(acc[trl][tc][reg] * inv);
        }
      }
  } else {
    // K waves (o 64..127 -> m 0..63): EK[m][n] + Ksum atomics
#pragma unroll
    for (int trl = 0; trl < 2; ++trl)
#pragma unroll
      for (int reg = 0; reg < 4; ++reg) {
        int m = (w - 2) * 32 + trl * 16 + quad * 4 + reg;
        float p = 0.f;
#pragma unroll
        for (int tc = 0; tc < 8; ++tc) {
          int n = tc * 16 + l15;
          float val = acc[trl][tc][reg] * invk[n];
          EK[m * 136 + n] = f2bf(val);
          p += val;
        }
        p += __shfl_xor(p, 1);
        p += __shfl_xor(p, 2);
        p += __shfl_xor(p, 4);
        p += __shfl_xor(p, 8);
        if (l15 == 0) atomicAdd(Ksum + b * 64 + m, p);
      }
  }
  __syncthreads();

  // cooperative coalesced global stores
  unsigned short* qdst = QnT + ((size_t)b * 4096 + n0) * 64;
#pragma unroll
  for (int p = 0; p < 4; ++p) {
    int idx = t + p * 256;
    int row = idx >> 3, seg = idx & 7;
    *(short8_t*)(qdst + row * 64 + seg * 8) = *(const short8_t*)(EQ + row * 72 + seg * 8);
  }
  unsigned short* kdst = KnG + (size_t)b * 64 * 4096 + n0;
#pragma unroll
  for (int p = 0; p < 4; ++p) {
    int idx = t + p * 256;
    int row = idx >> 4, seg = idx & 15;
    *(short8_t*)(kdst + (size_t)row * 4096 + seg * 8) =
        *(const short8_t*)(EK + row * 136 + seg * 8);
  }
}

// ---------------------------------------------------------------------------
// k_t:  T[b][64 m][512 k] += sum_n Kn[m,n]*x[k,n]   (split-K over n, atomics)
// also xsum[b][k] = sum_n x[k,n] (each x element loaded exactly once in grid)
// grid (8 nsplits, 4 ctiles, 16 batches), 256 threads.
// ---------------------------------------------------------------------------
__launch_bounds__(256, 2)
__global__ void k_t(const float* __restrict__ x, const unsigned short* __restrict__ KnG,
                    float* __restrict__ T, float* __restrict__ xsum) {
  __shared__ __align__(16) unsigned char smem[15360];
  unsigned short* SA = (unsigned short*)smem;            // 64 rows x 40 shorts (Kn)
  unsigned short* SB = (unsigned short*)(smem + 5120);   // 128 rows x 40 shorts (x)
  const int t = threadIdx.x;
  const int lane = t & 63, w = t >> 6;
  const int l15 = lane & 15, quad = lane >> 4;
  const int ns = blockIdx.x, ct = blockIdx.y, b = blockIdx.z;
  const int c0 = ct * 128;
  const float* xb = x + (size_t)b * 512 * 4096;
  const unsigned short* Knb = KnG + (size_t)b * 64 * 4096;

  f32x4 acc[4][2];
#pragma unroll
  for (int i = 0; i < 4; ++i)
#pragma unroll
    for (int j = 0; j < 2; ++j) acc[i][j] = (f32x4){0.f, 0.f, 0.f, 0.f};

  const int crow = t >> 1, half = t & 1;
  float xs = 0.f;

  for (int ch = 0; ch < 16; ++ch) {
    const int nb = ns * 512 + ch * 32;
    __syncthreads();
    {  // stage A: Kn rows (natural layout, n contiguous)
      int m = t >> 2, seg = t & 3;
      *(short8_t*)(SA + m * 40 + seg * 8) =
          *(const short8_t*)(Knb + (size_t)m * 4096 + nb + seg * 8);
    }
    {  // stage B: x rows (natural layout), fp32 -> bf16, + xsum partials
      const float* src = xb + (size_t)(c0 + crow) * 4096 + nb + half * 16;
      const f32x4* s4 = (const f32x4*)src;
      f32x4 f0 = s4[0], f1 = s4[1], f2 = s4[2], f3 = s4[3];
      short8_t v0, v1;
#pragma unroll
      for (int i = 0; i < 4; ++i) { xs += f0[i]; v0[i] = (short)f2bf(f0[i]); }
#pragma unroll
      for (int i = 0; i < 4; ++i) { xs += f1[i]; v0[4 + i] = (short)f2bf(f1[i]); }
#pragma unroll
      for (int i = 0; i < 4; ++i) { xs += f2[i]; v1[i] = (short)f2bf(f2[i]); }
#pragma unroll
      for (int i = 0; i < 4; ++i) { xs += f3[i]; v1[4 + i] = (short)f2bf(f3[i]); }
      *(short8_t*)(SB + crow * 40 + half * 16)     = v0;
      *(short8_t*)(SB + crow * 40 + half * 16 + 8) = v1;
    }
    __syncthreads();
    short8_t af[4];
#pragma unroll
    for (int tm = 0; tm < 4; ++tm)
      af[tm] = *(const short8_t*)(SA + (tm * 16 + l15) * 40 + quad * 8);
#pragma unroll
    for (int tcl = 0; tcl < 2; ++tcl) {
      short8_t bfr = *(const short8_t*)(SB + (w * 32 + tcl * 16 + l15) * 40 + quad * 8);
#pragma unroll
      for (int tm = 0; tm < 4; ++tm) acc[tm][tcl] = MFMA(af[tm], bfr, acc[tm][tcl]);
    }
  }
  // xsum: pair-combine (lanes 2k,2k+1 share crow) then one atomic
  xs += __shfl_xor(xs, 1);
  if (half == 0) atomicAdd(xsum + b * 512 + c0 + crow, xs);
  // T accumulation
#pragma unroll
  for (int tm = 0; tm < 4; ++tm)
#pragma unroll
    for (int tcl = 0; tcl < 2; ++tcl)
#pragma unroll
      for (int reg = 0; reg < 4; ++reg) {
        int m = tm * 16 + quad * 4 + reg;
        int c = c0 + w * 32 + tcl * 16 + l15;
        atomicAdd(T + ((size_t)b * 64 + m) * 512 + c, acc[tm][tcl][reg]);
      }
}

// ---------------------------------------------------------------------------
// k_mat: matrix[m][c] = sum_k T[m][k]*Wv[c][k] + bv[c]*Ksum[m]  -> matT[c][m] bf16
//        Vsum[c] = Wv[c,:]*xsum + 4096*bv[c]
// grid (16 cblocks, 16 batches), 256 threads; c-range 32 per block.
// ---------------------------------------------------------------------------
__launch_bounds__(256, 2)
__global__ void k_mat(const float* __restrict__ T, const float* __restrict__ Wv,
                      const float* __restrict__ bv, const float* __restrict__ xsum,
                      const float* __restrict__ Ksum,
                      unsigned short* __restrict__ matT, float* __restrict__ Vsum) {
  __shared__ __align__(16) unsigned char smem[27136];
  float* ST = (float*)smem;             // 64 x 68
  float* SW = (float*)(smem + 17408);   // 32 x 68
  float* SV = (float*)(smem + 26112);   // 256
  const int t = threadIdx.x;
  const int cb = blockIdx.x, b = blockIdx.y;
  const int c0 = cb * 32;
  const int m = t >> 2, cs = t & 3;
  float acc[8] = {0.f, 0.f, 0.f, 0.f, 0.f, 0.f, 0.f, 0.f};

  for (int kc = 0; kc < 8; ++kc) {
    __syncthreads();
#pragma unroll
    for (int p = 0; p < 4; ++p) {
      int idx = t + p * 256;
      int row = idx >> 4, f4 = idx & 15;
      *(f32x4*)(ST + row * 68 + f4 * 4) =
          *(const f32x4*)(T + ((size_t)b * 64 + row) * 512 + kc * 64 + f4 * 4);
    }
#pragma unroll
    for (int p = 0; p < 2; ++p) {
      int idx = t + p * 256;
      int row = idx >> 4, f4 = idx & 15;
      *(f32x4*)(SW + row * 68 + f4 * 4) =
          *(const f32x4*)(Wv + (size_t)(c0 + row) * 512 + kc * 64 + f4 * 4);
    }
    __syncthreads();
    for (int kk = 0; kk < 64; ++kk) {
      float tv = ST[m * 68 + kk];
#pragma unroll
      for (int j = 0; j < 8; ++j) acc[j] += tv * SW[(cs + j * 4) * 68 + kk];
    }
  }
  float ks = Ksum[b * 64 + m];
#pragma unroll
  for (int j = 0; j < 8; ++j) {
    int c = c0 + cs + j * 4;
    float mv = acc[j] + bv[c] * ks;
    matT[((size_t)b * 512 + c) * 64 + m] = f2bf(mv);
  }
  // Vsum
  {
    int cc = t >> 3, kp = t & 7;
    const float* wr = Wv + (size_t)(c0 + cc) * 512 + kp * 64;
    const float* xr = xsum + b * 512 + kp * 64;
    float s = 0.f;
    for (int i = 0; i < 64; ++i) s += wr[i] * xr[i];
    SV[cc * 8 + kp] = s;
  }
  __syncthreads();
  if (t < 32) {
    float s = 0.f;
#pragma unroll
    for (int i = 0; i < 8; ++i) s += SV[t * 8 + i];
    int c = c0 + t;
    Vsum[b * 512 + c] = s + 4096.0f * bv[c];
  }
}

// ---------------------------------------------------------------------------
// k_out: out[c][n] = gamma * tailor[n] * (Vsum[c] + sum_m matT[c][m]*Qn[m][n])
// K=64 MFMA GEMM; tailor computed in-block from staged Qn tile + Ksum.
// grid (32 ntiles, 4 ctiles, 16 batches), 256 threads; tile 128c x 128n.
// ---------------------------------------------------------------------------
__launch_bounds__(256, 2)
__global__ void k_out(const unsigned short* __restrict__ QnT,
                      const unsigned short* __restrict__ matT,
                      const float* __restrict__ Ksum, const float* __restrict__ Vsum,
                      const float* __restrict__ gamma, float* __restrict__ out) {
  __shared__ __align__(16) unsigned char smem[38144];
  unsigned short* SA = (unsigned short*)smem;             // 128 x 72 (matT tile)
  unsigned short* SB = (unsigned short*)(smem + 18432);   // 128 x 72 (QnT tile)
  float* Ksl  = (float*)(smem + 36864);                   // 64
  float* tail = (float*)(smem + 37120);                   // 128
  float* vs   = (float*)(smem + 37632);                   // 128
  const int t = threadIdx.x;
  const int lane = t & 63, w = t >> 6;
  const int l15 = lane & 15, quad = lane >> 4;
  const int nt = blockIdx.x, ct = blockIdx.y, b = blockIdx.z;
  const int n0 = nt * 128, c0 = ct * 128;

  const unsigned short* asrc = matT + ((size_t)b * 512 + c0) * 64;
  const unsigned short* bsrc = QnT + ((size_t)b * 4096 + n0) * 64;
#pragma unroll
  for (int p = 0; p < 4; ++p) {
    int idx = t + p * 256;
    int row = idx >> 3, seg = idx & 7;
    *(short8_t*)(SA + row * 72 + seg * 8) = *(const short8_t*)(asrc + row * 64 + seg * 8);
    *(short8_t*)(SB + row * 72 + seg * 8) = *(const short8_t*)(bsrc + row * 64 + seg * 8);
  }
  if (t < 64) Ksl[t] = Ksum[b * 64 + t];
  if (t >= 128) vs[t - 128] = Vsum[b * 512 + c0 + (t - 128)];
  __syncthreads();
  if (t < 128) {
    float d = 0.f;
#pragma unroll
    for (int mm = 0; mm < 64; ++mm) d += bf2f(SB[t * 72 + mm]) * Ksl[mm];
    tail[t] = 1.0f / fmaxf(4096.0f + d, 1e-6f);
  }

  f32x4 acc[2][8];
#pragma unroll
  for (int i = 0; i < 2; ++i)
#pragma unroll
    for (int j = 0; j < 8; ++j) acc[i][j] = (f32x4){0.f, 0.f, 0.f, 0.f};

#pragma unroll
  for (int s = 0; s < 2; ++s) {
    short8_t a0 = *(const short8_t*)(SA + (w * 32 + l15) * 72 + s * 32 + quad * 8);
    short8_t a1 = *(const short8_t*)(SA + (w * 32 + 16 + l15) * 72 + s * 32 + quad * 8);
#pragma unroll
    for (int tc = 0; tc < 8; ++tc) {
      short8_t bfr = *(const short8_t*)(SB + (tc * 16 + l15) * 72 + s * 32 + quad * 8);
      acc[0][tc] = MFMA(a0, bfr, acc[0][tc]);
      acc[1][tc] = MFMA(a1, bfr, acc[1][tc]);
    }
  }
  __syncthreads();
  const float g = gamma[0];
  float* ob = out + (size_t)b * 512 * 4096;
#pragma unroll
  for (int trl = 0; trl < 2; ++trl)
#pragma unroll
    for (int tc = 0; tc < 8; ++tc) {
      int n = tc * 16 + l15;
      float tl = tail[n] * g;
#pragma unroll
      for (int reg = 0; reg < 4; ++reg) {
        int cl = w * 32 + trl * 16 + quad * 4 + reg;
        float val = tl * (vs[cl] + acc[trl][tc][reg]);
        ob[(size_t)(c0 + cl) * 4096 + n0 + n] = val;
      }
    }
}

// ---------------------------------------------------------------------------
// workspace layout (bytes):
//   T      @ 0         : 16*64*512*4   = 2,097,152   (zeroed)
//   xsum   @ 2097152   : 16*512*4     = 32,768      (zeroed)
//   Ksum   @ 2129920   : 16*64*4      = 4,096       (zeroed)
//   Vsum   @ 2134016   : 32,768
//   Wqk    @ 2166784   : 128*512*2    = 131,072
//   matT   @ 2297856   : 16*512*64*2  = 1,048,576
//   QnT    @ 3346432   : 16*4096*64*2 = 8,388,608
//   Kn     @ 11735040  : 8,388,608
//   total ~20.2 MB
// ---------------------------------------------------------------------------
extern "C" void kernel_launch(void* const* d_in, const int* in_sizes, int n_in,
                              void* d_out, int out_size, void* d_ws, size_t ws_size,
                              hipStream_t stream) {
  const float* x     = (const float*)d_in[0];
  const float* Wq    = (const float*)d_in[1];
  const float* bq    = (const float*)d_in[2];
  const float* Wk    = (const float*)d_in[3];
  const float* bk    = (const float*)d_in[4];
  const float* Wv    = (const float*)d_in[5];
  const float* bv    = (const float*)d_in[6];
  const float* gamma = (const float*)d_in[7];
  float* out = (float*)d_out;
  char* ws = (char*)d_ws;

  float* T    = (float*)(ws + 0);
  float* xsum = (float*)(ws + 2097152);
  float* Ksum = (float*)(ws + 2129920);
  float* Vsum = (float*)(ws + 2134016);
  unsigned short* Wqk  = (unsigned short*)(ws + 2166784);
  unsigned short* matT = (unsigned short*)(ws + 2297856);
  unsigned short* QnT  = (unsigned short*)(ws + 3346432);
  unsigned short* Kn   = (unsigned short*)(ws + 11735040);

  hipMemsetAsync(ws, 0, 2134016, stream);
  k_prep<<<256, 256, 0, stream>>>(Wq, Wk, Wqk);
  k_qk<<<dim3(32, 16), 256, 0, stream>>>(x, Wqk, bq, bk, QnT, Kn, Ksum);
  k_t<<<dim3(8, 4, 16), 256, 0, stream>>>(x, Kn, T, xsum);
  k_mat<<<dim3(16, 16), 256, 0, stream>>>(T, Wv, bv, xsum, Ksum, matT, Vsum);
  k_out<<<dim3(32, 4, 16), 256, 0, stream>>>(QnT, matT, Ksum, Vsum, gamma, out);
}

// Round 2
// 322.853 us; speedup vs baseline: 1.0038x; 1.0038x over previous
//
#include <hip/hip_runtime.h>

// ---------------------------------------------------------------------------
// Attention_33638183862624  (linear "Taylor-softmax" attention)
// B=16, C=512, CQK=64, N=4096.  fp32 in/out, bf16 MFMA internally.
//   T[m,k]   = sum_n Kn[m,n] x[k,n]
//   matrix   = T * Wv^T + bv (x) Ksum
//   Vsum[c]  = Wv[c,:]*xsum + N*bv[c]
//   out[c,n] = gamma * tailor[n] * (Vsum[c] + sum_m Qn[m,n]*matrix[m,c])
// R2: k_qk/k_t restructured -> BK=64, register prefetch + LDS double buffer,
//     ONE __syncthreads per K-chunk (pending reg-loads need no vmcnt drain).
// ---------------------------------------------------------------------------

typedef __attribute__((ext_vector_type(8))) short short8_t;
typedef __attribute__((ext_vector_type(4))) float f32x4;

__device__ __forceinline__ unsigned short f2bf(float f) {
  union { float f; unsigned u; } v; v.f = f;
  unsigned r = v.u + 0x7FFFu + ((v.u >> 16) & 1u);   // RNE
  return (unsigned short)(r >> 16);
}
__device__ __forceinline__ float bf2f(unsigned short h) {
  union { unsigned u; float f; } v; v.u = ((unsigned)h) << 16;
  return v.f;
}

#define MFMA(a, b, c) __builtin_amdgcn_mfma_f32_16x16x32_bf16((a), (b), (c), 0, 0, 0)

// ---------------------------------------------------------------------------
// k_prep: pack Wq (rows 0..63) and Wk (rows 64..127) into bf16 [128][512]
// ---------------------------------------------------------------------------
__global__ void k_prep(const float* __restrict__ Wq, const float* __restrict__ Wk,
                       unsigned short* __restrict__ Wqk) {
  int idx = blockIdx.x * 256 + threadIdx.x;       // 65536 total
  int o = idx >> 9, c = idx & 511;
  float v = (o < 64) ? Wq[o * 512 + c] : Wk[(o - 64) * 512 + c];
  Wqk[idx] = f2bf(v);
}

// ---------------------------------------------------------------------------
// k_qk: per batch GEMM  QK[128 o][4096 n] = Wqk[128][512] * x[512][4096]
// tile 128o x 128n, BK=64, dbuf+prefetch.  Fused: bias, col L2 norm,
// QnT[b][n][64] bf16 (transposed), Kn[b][64][n] bf16, Ksum atomics.
// grid (32 ntiles, 16 batches), 256 threads.
// ---------------------------------------------------------------------------
__launch_bounds__(256, 2)
__global__ void k_qk(const float* __restrict__ x, const unsigned short* __restrict__ Wqk,
                     const float* __restrict__ bq, const float* __restrict__ bk,
                     unsigned short* __restrict__ QnT, unsigned short* __restrict__ KnG,
                     float* __restrict__ Ksum) {
  __shared__ __align__(16) unsigned char smem[77312];
  unsigned short* SAb[2] = {(unsigned short*)(smem + 0),
                            (unsigned short*)(smem + 18432)};   // 128 x 72 each
  unsigned short* SBb[2] = {(unsigned short*)(smem + 36864),
                            (unsigned short*)(smem + 55296)};   // 128 x 72 each
  unsigned short* EQ = (unsigned short*)(smem + 0);       // 128 x 72 (epilogue)
  unsigned short* EK = (unsigned short*)(smem + 18432);   // 64 x 136 (epilogue)
  float* ssq   = (float*)(smem + 73728);                  // [4][128]
  float* invq  = (float*)(smem + 75776);                  // [128]
  float* invk  = (float*)(smem + 76288);                  // [128]
  float* biasL = (float*)(smem + 76800);                  // [128]

  const int t = threadIdx.x;
  const int lane = t & 63, w = t >> 6;
  const int l15 = lane & 15, quad = lane >> 4;
  const int nt = blockIdx.x, b = blockIdx.y;
  const int n0 = nt * 128;
  const float* xb = x + (size_t)b * 512 * 4096;

  if (t < 128) biasL[t] = (t < 64) ? bq[t] : bk[t - 64];

  f32x4 acc[2][8];
#pragma unroll
  for (int i = 0; i < 2; ++i)
#pragma unroll
    for (int j = 0; j < 8; ++j) acc[i][j] = (f32x4){0.f, 0.f, 0.f, 0.f};

  const int nB = t & 127;     // column handled by this thread in B-staging
  const int cgB = t >> 7;     // 0/1 (32 c's each)
  const float* bsrc0 = xb + (size_t)(cgB * 32) * 4096 + n0 + nB;

  short8_t apre[4];
  float bpre[32];

#define QK_LOADA(kc_) do {                                                     \
    const int c0_ = (kc_) * 64;                                                \
    _Pragma("unroll")                                                          \
    for (int p = 0; p < 4; ++p) {                                              \
      int gid = t + p * 256; int o_ = gid >> 3, cg = gid & 7;                  \
      apre[p] = *(const short8_t*)(Wqk + o_ * 512 + c0_ + cg * 8);             \
    } } while (0)

#define QK_LOADB(kc_) do {                                                     \
    const float* s_ = bsrc0 + (size_t)(kc_) * 64 * 4096;                       \
    _Pragma("unroll")                                                          \
    for (int i = 0; i < 32; ++i) bpre[i] = s_[(size_t)i * 4096];               \
    } while (0)

#define QK_STORE(pb) do {                                                      \
    unsigned short* SAp = SAb[pb]; unsigned short* SBp = SBb[pb];              \
    _Pragma("unroll")                                                          \
    for (int p = 0; p < 4; ++p) {                                              \
      int gid = t + p * 256; int o_ = gid >> 3, cg = gid & 7;                  \
      *(short8_t*)(SAp + o_ * 72 + cg * 8) = apre[p];                          \
    }                                                                          \
    _Pragma("unroll")                                                          \
    for (int j = 0; j < 4; ++j) {                                              \
      short8_t v_;                                                             \
      _Pragma("unroll")                                                        \
      for (int e = 0; e < 8; ++e) v_[e] = (short)f2bf(bpre[j * 8 + e]);        \
      *(short8_t*)(SBp + nB * 72 + cgB * 32 + j * 8) = v_;                     \
    } } while (0)

#define QK_MM(pb) do {                                                         \
    const unsigned short* SAp = SAb[pb]; const unsigned short* SBp = SBb[pb];  \
    _Pragma("unroll")                                                          \
    for (int s = 0; s < 2; ++s) {                                              \
      short8_t a0 = *(const short8_t*)(SAp + (w * 32 + l15) * 72 + s * 32 + quad * 8);      \
      short8_t a1 = *(const short8_t*)(SAp + (w * 32 + 16 + l15) * 72 + s * 32 + quad * 8); \
      _Pragma("unroll")                                                        \
      for (int tc = 0; tc < 8; ++tc) {                                         \
        short8_t bf_ = *(const short8_t*)(SBp + (tc * 16 + l15) * 72 + s * 32 + quad * 8);  \
        acc[0][tc] = MFMA(a0, bf_, acc[0][tc]);                                \
        acc[1][tc] = MFMA(a1, bf_, acc[1][tc]);                                \
      } } } while (0)

  QK_LOADA(0); QK_LOADB(0);
#pragma unroll
  for (int kc = 0; kc < 8; ++kc) {
    const int pb = kc & 1;
    QK_STORE(pb);
    if (kc < 7) { QK_LOADA(kc + 1); QK_LOADB(kc + 1); }
    __syncthreads();
    QK_MM(pb);
  }
  __syncthreads();

  // add bias (per output channel o)
#pragma unroll
  for (int trl = 0; trl < 2; ++trl)
#pragma unroll
    for (int reg = 0; reg < 4; ++reg) {
      int o = w * 32 + trl * 16 + quad * 4 + reg;
      float bias = biasL[o];
#pragma unroll
      for (int tc = 0; tc < 8; ++tc) acc[trl][tc][reg] += bias;
    }

  // per-column sum of squares: reduce this wave's 32-o slice per column
#pragma unroll
  for (int tc = 0; tc < 8; ++tc) {
    float v = 0.f;
#pragma unroll
    for (int trl = 0; trl < 2; ++trl)
#pragma unroll
      for (int reg = 0; reg < 4; ++reg) {
        float q = acc[trl][tc][reg];
        v += q * q;
      }
    v += __shfl_xor(v, 16);
    v += __shfl_xor(v, 32);
    if (quad == 0) ssq[w * 128 + tc * 16 + l15] = v;
  }
  __syncthreads();
  if (t < 128) {
    float qs = ssq[t] + ssq[128 + t];
    float ks = ssq[256 + t] + ssq[384 + t];
    invq[t] = 1.0f / fmaxf(sqrtf(qs), 1e-6f);
    invk[t] = 1.0f / fmaxf(sqrtf(ks), 1e-6f);
  }
  __syncthreads();

  if (w < 2) {
    // Q waves (o 0..63): write normalized, transposed, into EQ[n][o]
#pragma unroll
    for (int trl = 0; trl < 2; ++trl)
#pragma unroll
      for (int tc = 0; tc < 8; ++tc) {
        int n = tc * 16 + l15;
        float inv = invq[n];
#pragma unroll
        for (int reg = 0; reg < 4; ++reg) {
          int o = w * 32 + trl * 16 + quad * 4 + reg;
          EQ[n * 72 + o] = f2bf(acc[trl][tc][reg] * inv);
        }
      }
  } else {
    // K waves (o 64..127 -> m 0..63): EK[m][n] + Ksum atomics
#pragma unroll
    for (int trl = 0; trl < 2; ++trl)
#pragma unroll
      for (int reg = 0; reg < 4; ++reg) {
        int m = (w - 2) * 32 + trl * 16 + quad * 4 + reg;
        float p = 0.f;
#pragma unroll
        for (int tc = 0; tc < 8; ++tc) {
          int n = tc * 16 + l15;
          float val = acc[trl][tc][reg] * invk[n];
          EK[m * 136 + n] = f2bf(val);
          p += val;
        }
        p += __shfl_xor(p, 1);
        p += __shfl_xor(p, 2);
        p += __shfl_xor(p, 4);
        p += __shfl_xor(p, 8);
        if (l15 == 0) atomicAdd(Ksum + b * 64 + m, p);
      }
  }
  __syncthreads();

  // cooperative coalesced global stores
  unsigned short* qdst = QnT + ((size_t)b * 4096 + n0) * 64;
#pragma unroll
  for (int p = 0; p < 4; ++p) {
    int idx = t + p * 256;
    int row = idx >> 3, seg = idx & 7;
    *(short8_t*)(qdst + row * 64 + seg * 8) = *(const short8_t*)(EQ + row * 72 + seg * 8);
  }
  unsigned short* kdst = KnG + (size_t)b * 64 * 4096 + n0;
#pragma unroll
  for (int p = 0; p < 4; ++p) {
    int idx = t + p * 256;
    int row = idx >> 4, seg = idx & 15;
    *(short8_t*)(kdst + (size_t)row * 4096 + seg * 8) =
        *(const short8_t*)(EK + row * 136 + seg * 8);
  }
#undef QK_LOADA
#undef QK_LOADB
#undef QK_STORE
#undef QK_MM
}

// ---------------------------------------------------------------------------
// k_t:  T[b][64 m][512 k] += sum_n Kn[m,n]*x[k,n]   (split-K over n, atomics)
// BK=64 chunks, dbuf+prefetch; xsum[b][k] folded in.
// grid (8 nsplits, 4 ctiles, 16 batches), 256 threads.
// ---------------------------------------------------------------------------
__launch_bounds__(256, 2)
__global__ void k_t(const float* __restrict__ x, const unsigned short* __restrict__ KnG,
                    float* __restrict__ T, float* __restrict__ xsum) {
  __shared__ __align__(16) unsigned char smem[55296];
  unsigned short* SAb[2] = {(unsigned short*)(smem + 0),
                            (unsigned short*)(smem + 9216)};    // 64 x 72 each
  unsigned short* SBb[2] = {(unsigned short*)(smem + 18432),
                            (unsigned short*)(smem + 36864)};   // 128 x 72 each
  const int t = threadIdx.x;
  const int lane = t & 63, w = t >> 6;
  const int l15 = lane & 15, quad = lane >> 4;
  const int ns = blockIdx.x, ct = blockIdx.y, b = blockIdx.z;
  const int c0 = ct * 128;
  const float* xb = x + (size_t)b * 512 * 4096;
  const unsigned short* Knb = KnG + (size_t)b * 64 * 4096 + ns * 512;

  f32x4 acc[4][2];
#pragma unroll
  for (int i = 0; i < 4; ++i)
#pragma unroll
    for (int j = 0; j < 2; ++j) acc[i][j] = (f32x4){0.f, 0.f, 0.f, 0.f};

  const int row = t >> 1, half = t & 1;
  float xs = 0.f;
  const float* bbase = xb + (size_t)(c0 + row) * 4096 + ns * 512 + half * 32;

  short8_t apre[2];
  f32x4 bpre[8];

#define T_LOADA(ch_) do {                                                      \
    _Pragma("unroll")                                                          \
    for (int p = 0; p < 2; ++p) {                                              \
      int gid = t + p * 256; int m_ = gid >> 3, cg = gid & 7;                  \
      apre[p] = *(const short8_t*)(Knb + (size_t)m_ * 4096 + (ch_) * 64 + cg * 8); \
    } } while (0)

#define T_LOADB(ch_) do {                                                      \
    const float* s_ = bbase + (ch_) * 64;                                      \
    _Pragma("unroll")                                                          \
    for (int q = 0; q < 8; ++q) bpre[q] = *(const f32x4*)(s_ + q * 4);         \
    } while (0)

#define T_STORE(pb) do {                                                       \
    unsigned short* SAp = SAb[pb]; unsigned short* SBp = SBb[pb];              \
    _Pragma("unroll")                                                          \
    for (int p = 0; p < 2; ++p) {                                              \
      int gid = t + p * 256; int m_ = gid >> 3, cg = gid & 7;                  \
      *(short8_t*)(SAp + m_ * 72 + cg * 8) = apre[p];                          \
    }                                                                          \
    _Pragma("unroll")                                                          \
    for (int j = 0; j < 4; ++j) {                                              \
      short8_t v_;                                                             \
      _Pragma("unroll")                                                        \
      for (int e = 0; e < 4; ++e) {                                            \
        float f0 = bpre[j * 2][e], f1 = bpre[j * 2 + 1][e];                    \
        xs += f0 + f1;                                                         \
        v_[e] = (short)f2bf(f0); v_[4 + e] = (short)f2bf(f1);                  \
      }                                                                        \
      *(short8_t*)(SBp + row * 72 + half * 32 + j * 8) = v_;                   \
    } } while (0)

#define T_MM(pb) do {                                                          \
    const unsigned short* SAp = SAb[pb]; const unsigned short* SBp = SBb[pb];  \
    _Pragma("unroll")                                                          \
    for (int s = 0; s < 2; ++s) {                                              \
      short8_t af[4];                                                          \
      _Pragma("unroll")                                                        \
      for (int tm = 0; tm < 4; ++tm)                                           \
        af[tm] = *(const short8_t*)(SAp + (tm * 16 + l15) * 72 + s * 32 + quad * 8); \
      _Pragma("unroll")                                                        \
      for (int tcl = 0; tcl < 2; ++tcl) {                                      \
        short8_t bf_ = *(const short8_t*)(SBp + (w * 32 + tcl * 16 + l15) * 72 + s * 32 + quad * 8); \
        _Pragma("unroll")                                                      \
        for (int tm = 0; tm < 4; ++tm) acc[tm][tcl] = MFMA(af[tm], bf_, acc[tm][tcl]); \
      } } } while (0)

  // NOTE: bpre[j*2][e] ordering: v_ holds 8 consecutive n (two f32x4's)
  T_LOADA(0); T_LOADB(0);
#pragma unroll
  for (int ch = 0; ch < 8; ++ch) {
    const int pb = ch & 1;
    T_STORE(pb);
    if (ch < 7) { T_LOADA(ch + 1); T_LOADB(ch + 1); }
    __syncthreads();
    T_MM(pb);
  }

  // xsum: lanes (2k,2k+1) share row -> pair-combine, one atomic
  xs += __shfl_xor(xs, 1);
  if (half == 0) atomicAdd(xsum + b * 512 + c0 + row, xs);
  // T accumulation
#pragma unroll
  for (int tm = 0; tm < 4; ++tm)
#pragma unroll
    for (int tcl = 0; tcl < 2; ++tcl)
#pragma unroll
      for (int reg = 0; reg < 4; ++reg) {
        int m = tm * 16 + quad * 4 + reg;
        int c = c0 + w * 32 + tcl * 16 + l15;
        atomicAdd(T + ((size_t)b * 64 + m) * 512 + c, acc[tm][tcl][reg]);
      }
#undef T_LOADA
#undef T_LOADB
#undef T_STORE
#undef T_MM
}

// ---------------------------------------------------------------------------
// k_mat: matrix[m][c] = sum_k T[m][k]*Wv[c][k] + bv[c]*Ksum[m]  -> matT[c][m] bf16
//        Vsum[c] = Wv[c,:]*xsum + 4096*bv[c]
// grid (16 cblocks, 16 batches), 256 threads; c-range 32 per block.
// ---------------------------------------------------------------------------
__launch_bounds__(256, 2)
__global__ void k_mat(const float* __restrict__ T, const float* __restrict__ Wv,
                      const float* __restrict__ bv, const float* __restrict__ xsum,
                      const float* __restrict__ Ksum,
                      unsigned short* __restrict__ matT, float* __restrict__ Vsum) {
  __shared__ __align__(16) unsigned char smem[27136];
  float* ST = (float*)smem;             // 64 x 68
  float* SW = (float*)(smem + 17408);   // 32 x 68
  float* SV = (float*)(smem + 26112);   // 256
  const int t = threadIdx.x;
  const int cb = blockIdx.x, b = blockIdx.y;
  const int c0 = cb * 32;
  const int m = t >> 2, cs = t & 3;
  float acc[8] = {0.f, 0.f, 0.f, 0.f, 0.f, 0.f, 0.f, 0.f};

  for (int kc = 0; kc < 8; ++kc) {
    __syncthreads();
#pragma unroll
    for (int p = 0; p < 4; ++p) {
      int idx = t + p * 256;
      int row = idx >> 4, f4 = idx & 15;
      *(f32x4*)(ST + row * 68 + f4 * 4) =
          *(const f32x4*)(T + ((size_t)b * 64 + row) * 512 + kc * 64 + f4 * 4);
    }
#pragma unroll
    for (int p = 0; p < 2; ++p) {
      int idx = t + p * 256;
      int row = idx >> 4, f4 = idx & 15;
      *(f32x4*)(SW + row * 68 + f4 * 4) =
          *(const f32x4*)(Wv + (size_t)(c0 + row) * 512 + kc * 64 + f4 * 4);
    }
    __syncthreads();
    for (int kk = 0; kk < 64; ++kk) {
      float tv = ST[m * 68 + kk];
#pragma unroll
      for (int j = 0; j < 8; ++j) acc[j] += tv * SW[(cs + j * 4) * 68 + kk];
    }
  }
  float ks = Ksum[b * 64 + m];
#pragma unroll
  for (int j = 0; j < 8; ++j) {
    int c = c0 + cs + j * 4;
    float mv = acc[j] + bv[c] * ks;
    matT[((size_t)b * 512 + c) * 64 + m] = f2bf(mv);
  }
  // Vsum
  {
    int cc = t >> 3, kp = t & 7;
    const float* wr = Wv + (size_t)(c0 + cc) * 512 + kp * 64;
    const float* xr = xsum + b * 512 + kp * 64;
    float s = 0.f;
    for (int i = 0; i < 64; ++i) s += wr[i] * xr[i];
    SV[cc * 8 + kp] = s;
  }
  __syncthreads();
  if (t < 32) {
    float s = 0.f;
#pragma unroll
    for (int i = 0; i < 8; ++i) s += SV[t * 8 + i];
    int c = c0 + t;
    Vsum[b * 512 + c] = s + 4096.0f * bv[c];
  }
}

// ---------------------------------------------------------------------------
// k_out: out[c][n] = gamma * tailor[n] * (Vsum[c] + sum_m matT[c][m]*Qn[m][n])
// K=64 MFMA GEMM; tailor computed in-block from staged Qn tile + Ksum.
// grid (32 ntiles, 4 ctiles, 16 batches), 256 threads; tile 128c x 128n.
// ---------------------------------------------------------------------------
__launch_bounds__(256, 2)
__global__ void k_out(const unsigned short* __restrict__ QnT,
                      const unsigned short* __restrict__ matT,
                      const float* __restrict__ Ksum, const float* __restrict__ Vsum,
                      const float* __restrict__ gamma, float* __restrict__ out) {
  __shared__ __align__(16) unsigned char smem[38144];
  unsigned short* SA = (unsigned short*)smem;             // 128 x 72 (matT tile)
  unsigned short* SB = (unsigned short*)(smem + 18432);   // 128 x 72 (QnT tile)
  float* Ksl  = (float*)(smem + 36864);                   // 64
  float* tail = (float*)(smem + 37120);                   // 128
  float* vs   = (float*)(smem + 37632);                   // 128
  const int t = threadIdx.x;
  const int lane = t & 63, w = t >> 6;
  const int l15 = lane & 15, quad = lane >> 4;
  const int nt = blockIdx.x, ct = blockIdx.y, b = blockIdx.z;
  const int n0 = nt * 128, c0 = ct * 128;

  const unsigned short* asrc = matT + ((size_t)b * 512 + c0) * 64;
  const unsigned short* bsrc = QnT + ((size_t)b * 4096 + n0) * 64;
#pragma unroll
  for (int p = 0; p < 4; ++p) {
    int idx = t + p * 256;
    int row = idx >> 3, seg = idx & 7;
    *(short8_t*)(SA + row * 72 + seg * 8) = *(const short8_t*)(asrc + row * 64 + seg * 8);
    *(short8_t*)(SB + row * 72 + seg * 8) = *(const short8_t*)(bsrc + row * 64 + seg * 8);
  }
  if (t < 64) Ksl[t] = Ksum[b * 64 + t];
  if (t >= 128) vs[t - 128] = Vsum[b * 512 + c0 + (t - 128)];
  __syncthreads();
  if (t < 128) {
    float d = 0.f;
#pragma unroll
    for (int mm = 0; mm < 64; ++mm) d += bf2f(SB[t * 72 + mm]) * Ksl[mm];
    tail[t] = 1.0f / fmaxf(4096.0f + d, 1e-6f);
  }

  f32x4 acc[2][8];
#pragma unroll
  for (int i = 0; i < 2; ++i)
#pragma unroll
    for (int j = 0; j < 8; ++j) acc[i][j] = (f32x4){0.f, 0.f, 0.f, 0.f};

#pragma unroll
  for (int s = 0; s < 2; ++s) {
    short8_t a0 = *(const short8_t*)(SA + (w * 32 + l15) * 72 + s * 32 + quad * 8);
    short8_t a1 = *(const short8_t*)(SA + (w * 32 + 16 + l15) * 72 + s * 32 + quad * 8);
#pragma unroll
    for (int tc = 0; tc < 8; ++tc) {
      short8_t bfr = *(const short8_t*)(SB + (tc * 16 + l15) * 72 + s * 32 + quad * 8);
      acc[0][tc] = MFMA(a0, bfr, acc[0][tc]);
      acc[1][tc] = MFMA(a1, bfr, acc[1][tc]);
    }
  }
  __syncthreads();
  const float g = gamma[0];
  float* ob = out + (size_t)b * 512 * 4096;
#pragma unroll
  for (int trl = 0; trl < 2; ++trl)
#pragma unroll
    for (int tc = 0; tc < 8; ++tc) {
      int n = tc * 16 + l15;
      float tl = tail[n] * g;
#pragma unroll
      for (int reg = 0; reg < 4; ++reg) {
        int cl = w * 32 + trl * 16 + quad * 4 + reg;
        float val = tl * (vs[cl] + acc[trl][tc][reg]);
        ob[(size_t)(c0 + cl) * 4096 + n0 + n] = val;
      }
    }
}

// ---------------------------------------------------------------------------
// workspace layout (bytes):
//   T      @ 0         : 16*64*512*4   = 2,097,152   (zeroed)
//   xsum   @ 2097152   : 16*512*4     = 32,768      (zeroed)
//   Ksum   @ 2129920   : 16*64*4      = 4,096       (zeroed)
//   Vsum   @ 2134016   : 32,768
//   Wqk    @ 2166784   : 128*512*2    = 131,072
//   matT   @ 2297856   : 16*512*64*2  = 1,048,576
//   QnT    @ 3346432   : 16*4096*64*2 = 8,388,608
//   Kn     @ 11735040  : 8,388,608
// ---------------------------------------------------------------------------
extern "C" void kernel_launch(void* const* d_in, const int* in_sizes, int n_in,
                              void* d_out, int out_size, void* d_ws, size_t ws_size,
                              hipStream_t stream) {
  const float* x     = (const float*)d_in[0];
  const float* Wq    = (const float*)d_in[1];
  const float* bq    = (const float*)d_in[2];
  const float* Wk    = (const float*)d_in[3];
  const float* bk    = (const float*)d_in[4];
  const float* Wv    = (const float*)d_in[5];
  const float* bv    = (const float*)d_in[6];
  const float* gamma = (const float*)d_in[7];
  float* out = (float*)d_out;
  char* ws = (char*)d_ws;

  float* T    = (float*)(ws + 0);
  float* xsum = (float*)(ws + 2097152);
  float* Ksum = (float*)(ws + 2129920);
  float* Vsum = (float*)(ws + 2134016);
  unsigned short* Wqk  = (unsigned short*)(ws + 2166784);
  unsigned short* matT = (unsigned short*)(ws + 2297856);
  unsigned short* QnT  = (unsigned short*)(ws + 3346432);
  unsigned short* Kn   = (unsigned short*)(ws + 11735040);

  hipMemsetAsync(ws, 0, 2134016, stream);
  k_prep<<<256, 256, 0, stream>>>(Wq, Wk, Wqk);
  k_qk<<<dim3(32, 16), 256, 0, stream>>>(x, Wqk, bq, bk, QnT, Kn, Ksum);
  k_t<<<dim3(8, 4, 16), 256, 0, stream>>>(x, Kn, T, xsum);
  k_mat<<<dim3(16, 16), 256, 0, stream>>>(T, Wv, bv, xsum, Ksum, matT, Vsum);
  k_out<<<dim3(32, 4, 16), 256, 0, stream>>>(QnT, matT, Ksum, Vsum, gamma, out);
}